// Round 14
// baseline (55.426 us; speedup 1.0000x reference)
//
#include <hip/hip_runtime.h>

// GPLoss: gradient-profile loss, scalar output.
// Main pass (R11 full-row-wave structure, VGPR-budget-fixed): 1536 blocks x
// 256 thr; block = one 32-row band. Wave w owns rows [q*32+8w, +8); lane owns
// 8 FULL-ROW cols (2 x float4/array). One wave spans the whole row -> 36 DPP
// per row (half of the 4-col layout), zero VMEM halo (shfl_down), cos fully
// in-register on lane 63. __launch_bounds__(256,2): VGPR budget 256 so the
// ~92 live values DON'T spill (R11 failure: compiler pinned 64 and spilled
// 186 MB). Col merge via float4 LDS ops (R11's scalar merge: 5.3M conflicts).
// colPart 96*16 slots = 18.9 MB (L3-safe, R8-proven).
// ws: colPart f32[96*16][6][512] ; rowPart f32[6144][2] ; dblk f64[192]

typedef float f32x4 __attribute__((ext_vector_type(4)));

#define DPP_ADD(x, ctrl, rmask) \
  x += __int_as_float(__builtin_amdgcn_update_dpp(0, __float_as_int(x), ctrl, rmask, 0xf, false))

__device__ __forceinline__ float wave_dpp_sum(float x){
  DPP_ADD(x, 0x111, 0xf);   // row_shr:1
  DPP_ADD(x, 0x112, 0xf);   // row_shr:2
  DPP_ADD(x, 0x114, 0xf);   // row_shr:4
  DPP_ADD(x, 0x118, 0xf);   // row_shr:8
  DPP_ADD(x, 0x142, 0xa);   // row_bcast:15 -> rows 1,3
  DPP_ADD(x, 0x143, 0xc);   // row_bcast:31 -> rows 2,3
  return x;                 // lane 63 holds the 64-lane sum
}

__device__ __forceinline__ float cos_sim(float d, float sx, float sr){
  float nx = fmaxf(sqrtf(sx), 1e-12f);
  float nr = fmaxf(sqrtf(sr), 1e-12f);
  return d / (nx * nr);
}

__global__ __launch_bounds__(256, 2) void gp_uni(
    const float* __restrict__ X, const float* __restrict__ R,
    float* __restrict__ rowPart, float* __restrict__ colPart)
{
  const int bid = blockIdx.x;
  const int p = bid >> 4, q = bid & 15;        // plane, 32-row band
  const int tid = threadIdx.x, w = tid >> 6, l = tid & 63;
  const size_t plane = (size_t)p * (512u * 512u);
  const float* xp = X + plane;
  const float* rp = R + plane;
  const int c = 8 * l;                          // cols c..c+7 (full row/wave)
  const bool tlast = (l == 63);                 // col 511: no f_v
  const int h0 = q*32 + w*8;                    // first row of this wave

  __shared__ float Abuf[6][512];                // 12 KB (waves 0,1)
  __shared__ float Bbuf[6][512];                // 12 KB (waves 2,3)

  float cv0[8], cv1[8], cv2[8], ch0[8], ch1[8], ch2[8];
  #pragma unroll
  for (int j = 0; j < 8; ++j){
    cv0[j]=0.f; cv1[j]=0.f; cv2[j]=0.f;
    ch0[j]=0.f; ch1[j]=0.f; ch2[j]=0.f;
  }
  float rsv = 0.f, rsh = 0.f;                   // valid on lane 63

  const float* xr = xp + (size_t)h0*512 + c;
  const float* rr = rp + (size_t)h0*512 + c;
  float4 xa = *(const float4*)xr, xb = *(const float4*)(xr+4);
  float4 ra = *(const float4*)rr, rb = *(const float4*)(rr+4);

  for (int k = 0; k < 8; ++k){
    const int h  = h0 + k;
    const int hn = (h+1 < 512) ? h+1 : 511;     // h==511: next==cur -> dh=0
    const float* xn = xp + (size_t)hn*512 + c;
    const float* rn = rp + (size_t)hn*512 + c;
    const float4 nxa = *(const float4*)xn, nxb = *(const float4*)(xn+4);
    const float4 nra = *(const float4*)rn, nrb = *(const float4*)(rn+4);

    // f_v halo: lane l needs col 8l+8 = lane (l+1)'s xa.x
    const float xhalo = __shfl_down(xa.x, 1, 64);
    const float rhalo = __shfl_down(ra.x, 1, 64);

    const float ax[8] = {xa.x,xa.y,xa.z,xa.w, xb.x,xb.y,xb.z,xb.w};
    const float ar[8] = {ra.x,ra.y,ra.z,ra.w, rb.x,rb.y,rb.z,rb.w};
    const float bx[8] = {nxa.x,nxa.y,nxa.z,nxa.w, nxb.x,nxb.y,nxb.z,nxb.w};
    const float br[8] = {nra.x,nra.y,nra.z,nra.w, nrb.x,nrb.y,nrb.z,nrb.w};

    float p0=0.f,p1=0.f,p2=0.f, q0=0.f,q1=0.f,q2=0.f;
    #pragma unroll
    for (int j = 0; j < 8; ++j){
      const float dv = (j<7) ? (ax[j]-ax[j+1]) : (tlast ? 0.f : (ax[7]-xhalo));
      const float ev = (j<7) ? (ar[j]-ar[j+1]) : (tlast ? 0.f : (ar[7]-rhalo));
      p0 = fmaf(dv,ev,p0); p1 = fmaf(dv,dv,p1); p2 = fmaf(ev,ev,p2);
      cv0[j] = fmaf(dv,ev,cv0[j]);
      cv1[j] = fmaf(dv,dv,cv1[j]);
      cv2[j] = fmaf(ev,ev,cv2[j]);
      const float dh = ax[j]-bx[j];
      const float eh = ar[j]-br[j];
      q0 = fmaf(dh,eh,q0); q1 = fmaf(dh,dh,q1); q2 = fmaf(eh,eh,q2);
      ch0[j] = fmaf(dh,eh,ch0[j]);
      ch1[j] = fmaf(dh,dh,ch1[j]);
      ch2[j] = fmaf(eh,eh,ch2[j]);
    }

    // full-row reduction: 6 independent DPP chains, sum lands in lane 63
    p0 = wave_dpp_sum(p0); p1 = wave_dpp_sum(p1); p2 = wave_dpp_sum(p2);
    q0 = wave_dpp_sum(q0); q1 = wave_dpp_sum(q1); q2 = wave_dpp_sum(q2);
    rsv += cos_sim(p0,p1,p2);                 // garbage on lanes<63, unused
    if (h < 511) rsh += cos_sim(q0,q1,q2);

    xa = nxa; xb = nxb; ra = nra; rb = nrb;
  }

  // ---- col merge: w0->A, w2->B ; then w1+=A, w3+=B ; store A+B (float4 ops)
  if (w == 0){
    *(float4*)&Abuf[0][c] = make_float4(cv0[0],cv0[1],cv0[2],cv0[3]);
    *(float4*)&Abuf[0][c+4] = make_float4(cv0[4],cv0[5],cv0[6],cv0[7]);
    *(float4*)&Abuf[1][c] = make_float4(cv1[0],cv1[1],cv1[2],cv1[3]);
    *(float4*)&Abuf[1][c+4] = make_float4(cv1[4],cv1[5],cv1[6],cv1[7]);
    *(float4*)&Abuf[2][c] = make_float4(cv2[0],cv2[1],cv2[2],cv2[3]);
    *(float4*)&Abuf[2][c+4] = make_float4(cv2[4],cv2[5],cv2[6],cv2[7]);
    *(float4*)&Abuf[3][c] = make_float4(ch0[0],ch0[1],ch0[2],ch0[3]);
    *(float4*)&Abuf[3][c+4] = make_float4(ch0[4],ch0[5],ch0[6],ch0[7]);
    *(float4*)&Abuf[4][c] = make_float4(ch1[0],ch1[1],ch1[2],ch1[3]);
    *(float4*)&Abuf[4][c+4] = make_float4(ch1[4],ch1[5],ch1[6],ch1[7]);
    *(float4*)&Abuf[5][c] = make_float4(ch2[0],ch2[1],ch2[2],ch2[3]);
    *(float4*)&Abuf[5][c+4] = make_float4(ch2[4],ch2[5],ch2[6],ch2[7]);
  } else if (w == 2){
    *(float4*)&Bbuf[0][c] = make_float4(cv0[0],cv0[1],cv0[2],cv0[3]);
    *(float4*)&Bbuf[0][c+4] = make_float4(cv0[4],cv0[5],cv0[6],cv0[7]);
    *(float4*)&Bbuf[1][c] = make_float4(cv1[0],cv1[1],cv1[2],cv1[3]);
    *(float4*)&Bbuf[1][c+4] = make_float4(cv1[4],cv1[5],cv1[6],cv1[7]);
    *(float4*)&Bbuf[2][c] = make_float4(cv2[0],cv2[1],cv2[2],cv2[3]);
    *(float4*)&Bbuf[2][c+4] = make_float4(cv2[4],cv2[5],cv2[6],cv2[7]);
    *(float4*)&Bbuf[3][c] = make_float4(ch0[0],ch0[1],ch0[2],ch0[3]);
    *(float4*)&Bbuf[3][c+4] = make_float4(ch0[4],ch0[5],ch0[6],ch0[7]);
    *(float4*)&Bbuf[4][c] = make_float4(ch1[0],ch1[1],ch1[2],ch1[3]);
    *(float4*)&Bbuf[4][c+4] = make_float4(ch1[4],ch1[5],ch1[6],ch1[7]);
    *(float4*)&Bbuf[5][c] = make_float4(ch2[0],ch2[1],ch2[2],ch2[3]);
    *(float4*)&Bbuf[5][c+4] = make_float4(ch2[4],ch2[5],ch2[6],ch2[7]);
  }
  __syncthreads();
  if (w == 1 || w == 3){
    float (*buf)[512] = (w == 1) ? Abuf : Bbuf;
    float4 t;
    t = *(float4*)&buf[0][c];   t.x+=cv0[0]; t.y+=cv0[1]; t.z+=cv0[2]; t.w+=cv0[3]; *(float4*)&buf[0][c]=t;
    t = *(float4*)&buf[0][c+4]; t.x+=cv0[4]; t.y+=cv0[5]; t.z+=cv0[6]; t.w+=cv0[7]; *(float4*)&buf[0][c+4]=t;
    t = *(float4*)&buf[1][c];   t.x+=cv1[0]; t.y+=cv1[1]; t.z+=cv1[2]; t.w+=cv1[3]; *(float4*)&buf[1][c]=t;
    t = *(float4*)&buf[1][c+4]; t.x+=cv1[4]; t.y+=cv1[5]; t.z+=cv1[6]; t.w+=cv1[7]; *(float4*)&buf[1][c+4]=t;
    t = *(float4*)&buf[2][c];   t.x+=cv2[0]; t.y+=cv2[1]; t.z+=cv2[2]; t.w+=cv2[3]; *(float4*)&buf[2][c]=t;
    t = *(float4*)&buf[2][c+4]; t.x+=cv2[4]; t.y+=cv2[5]; t.z+=cv2[6]; t.w+=cv2[7]; *(float4*)&buf[2][c+4]=t;
    t = *(float4*)&buf[3][c];   t.x+=ch0[0]; t.y+=ch0[1]; t.z+=ch0[2]; t.w+=ch0[3]; *(float4*)&buf[3][c]=t;
    t = *(float4*)&buf[3][c+4]; t.x+=ch0[4]; t.y+=ch0[5]; t.z+=ch0[6]; t.w+=ch0[7]; *(float4*)&buf[3][c+4]=t;
    t = *(float4*)&buf[4][c];   t.x+=ch1[0]; t.y+=ch1[1]; t.z+=ch1[2]; t.w+=ch1[3]; *(float4*)&buf[4][c]=t;
    t = *(float4*)&buf[4][c+4]; t.x+=ch1[4]; t.y+=ch1[5]; t.z+=ch1[6]; t.w+=ch1[7]; *(float4*)&buf[4][c+4]=t;
    t = *(float4*)&buf[5][c];   t.x+=ch2[0]; t.y+=ch2[1]; t.z+=ch2[2]; t.w+=ch2[3]; *(float4*)&buf[5][c]=t;
    t = *(float4*)&buf[5][c+4]; t.x+=ch2[4]; t.y+=ch2[5]; t.z+=ch2[6]; t.w+=ch2[7]; *(float4*)&buf[5][c+4]=t;
  }
  __syncthreads();
  {
    const f32x4* A4 = (const f32x4*)Abuf;
    const f32x4* B4 = (const f32x4*)Bbuf;
    f32x4* s4 = (f32x4*)(colPart + (size_t)bid * (6*512));
    #pragma unroll
    for (int i = 0; i < 3; ++i)
      s4[tid + 256*i] = A4[tid + 256*i] + B4[tid + 256*i];
  }

  if (l == 63){
    rowPart[(bid*4 + w)*2 + 0] = rsv;
    rowPart[(bid*4 + w)*2 + 1] = rsh;
  }
}

// ---------------- finish: reduce col partials over 16 slots ------------------
__global__ __launch_bounds__(256) void gp_cols(
    const float* __restrict__ colPart, double* __restrict__ dblk)
{
  const int p = blockIdx.x >> 1;
  const int f = blockIdx.x & 1;    // 0 = fv, 1 = fh
  const int tid = threadIdx.x;
  double acc = 0.0;
  for (int c = tid; c < 512; c += 256){
    float d = 0.f, a = 0.f, b = 0.f;
    #pragma unroll
    for (int s = 0; s < 16; ++s){
      const float* sp = colPart + ((size_t)(p*16 + s) * 6 + f*3) * 512;
      d += sp[c]; a += sp[512 + c]; b += sp[1024 + c];
    }
    acc += (double)cos_sim(d, a, b);   // fv col 511: cos(0,0,0)=0, harmless
  }
  #pragma unroll
  for (int m = 1; m < 64; m <<= 1) acc += __shfl_xor(acc, m, 64);
  __shared__ double ls[4];
  const int w = tid >> 6, l = tid & 63;
  if (l == 0) ls[w] = acc;
  __syncthreads();
  if (tid == 0) dblk[blockIdx.x] = ls[0] + ls[1] + ls[2] + ls[3];
}

__global__ __launch_bounds__(256) void gp_fin(
    const double* __restrict__ dblk, const float* __restrict__ rowPart,
    int nblk, float* __restrict__ out)
{
  const int tid = threadIdx.x;
  double rv = 0, rh = 0, cv = 0, ch = 0;
  for (int i = tid; i < nblk; i += 256){
    rv += (double)rowPart[2*i];
    rh += (double)rowPart[2*i+1];
  }
  for (int i = tid; i < 192; i += 256){
    if (i & 1) ch += dblk[i]; else cv += dblk[i];
  }
  #pragma unroll
  for (int m = 1; m < 64; m <<= 1){
    rv += __shfl_xor(rv, m, 64); rh += __shfl_xor(rh, m, 64);
    cv += __shfl_xor(cv, m, 64); ch += __shfl_xor(ch, m, 64);
  }
  __shared__ double ls[4][4];
  const int w = tid >> 6, l = tid & 63;
  if (l == 0){ ls[w][0]=rv; ls[w][1]=rh; ls[w][2]=cv; ls[w][3]=ch; }
  __syncthreads();
  if (tid == 0){
    double RV=0, RH=0, CV=0, CH=0;
    #pragma unroll
    for (int i = 0; i < 4; ++i){ RV+=ls[i][0]; RH+=ls[i][1]; CV+=ls[i][2]; CH+=ls[i][3]; }
    const double t = RV/512.0 + RH/511.0 + CV/511.0 + CH/512.0;
    out[0] = (float)(-t / 32.0);
  }
}

extern "C" void kernel_launch(void* const* d_in, const int* in_sizes, int n_in,
                              void* d_out, int out_size, void* d_ws, size_t ws_size,
                              hipStream_t stream) {
  const float* X = (const float*)d_in[0];
  const float* R = (const float*)d_in[1];
  float* out = (float*)d_out;

  float*  colPart = (float*)d_ws;                           // 96*16*6*512 f32
  float*  rowPart = colPart + (size_t)96*16*6*512;          // 6144*2 f32
  double* dblk    = (double*)(rowPart + (size_t)6144*2);    // 192 f64

  gp_uni <<<dim3(1536), dim3(256), 0, stream>>>(X, R, rowPart, colPart);
  gp_cols<<<dim3(192),  dim3(256), 0, stream>>>(colPart, dblk);
  gp_fin <<<dim3(1),    dim3(256), 0, stream>>>(dblk, rowPart, 6144, out);
}

// Round 15
// 50.563 us; speedup vs baseline: 1.0962x; 1.0962x over previous
//
#include <hip/hip_runtime.h>

// GPLoss: gradient-profile loss, scalar output.
// Main pass: R8's proven per-wave loop (16 rows x 256 cols, 4 cols/lane,
// scalar halo loads, 6 DPP chains/row) in 512-thread blocks: 768 blocks,
// block = one 64-row band (8 waves = 4 rowgrps x 2 colhalves). colPart
// halves to 768 slots = 9.4 MB (saves ~19 MB finisher traffic vs R8).
// ws: colPart f32[768][6][512] ; rowPart f32[768][2] ; dblk f64[192]

typedef float f32x4 __attribute__((ext_vector_type(4)));

#define DPP_ADD(x, ctrl, rmask) \
  x += __int_as_float(__builtin_amdgcn_update_dpp(0, __float_as_int(x), ctrl, rmask, 0xf, false))

__device__ __forceinline__ float wave_dpp_sum(float x){
  DPP_ADD(x, 0x111, 0xf);   // row_shr:1
  DPP_ADD(x, 0x112, 0xf);   // row_shr:2
  DPP_ADD(x, 0x114, 0xf);   // row_shr:4
  DPP_ADD(x, 0x118, 0xf);   // row_shr:8
  DPP_ADD(x, 0x142, 0xa);   // row_bcast:15 -> rows 1,3
  DPP_ADD(x, 0x143, 0xc);   // row_bcast:31 -> rows 2,3
  return x;                 // lane 63 holds the 64-lane sum
}

__device__ __forceinline__ float cos_sim(float d, float sx, float sr){
  float nx = fmaxf(sqrtf(sx), 1e-12f);
  float nr = fmaxf(sqrtf(sr), 1e-12f);
  return d / (nx * nr);
}

__global__ __launch_bounds__(512) void gp_uni(
    const float* __restrict__ X, const float* __restrict__ R,
    float* __restrict__ rowPart, float* __restrict__ colPart)
{
  const int bid = blockIdx.x;
  const int p = bid >> 3, q = bid & 7;         // plane, 64-row band
  const int tid = threadIdx.x, w = tid >> 6, l = tid & 63;
  const int rg = w >> 1;                        // row-group 0..3
  const int wp = w & 1;                         // col half: wp*256
  const size_t plane = (size_t)p * (512u * 512u);
  const float* xp = X + plane;
  const float* rp = R + plane;
  const int c  = wp*256 + 4*l;                  // cols c..c+3
  const int cn = (c+4 < 512) ? c+4 : 511;       // f_v halo col (clamped)
  const bool tlast = (c == 508);                // col 511: no f_v
  const int h0 = q*64 + rg*16;                  // first row of this wave

  __shared__ float Abuf[6][512];                // 12 KB (rowgrps 0,2)
  __shared__ float Bbuf[6][512];                // 12 KB (rowgrps 1,3)
  __shared__ float rowbuf[64][2][6];            // 3 KB row stats

  float cv0[4], cv1[4], cv2[4], ch0[4], ch1[4], ch2[4];
  #pragma unroll
  for (int j = 0; j < 4; ++j){
    cv0[j]=0.f; cv1[j]=0.f; cv2[j]=0.f;
    ch0[j]=0.f; ch1[j]=0.f; ch2[j]=0.f;
  }

  const float* xr0 = xp + (size_t)h0*512;
  const float* rr0 = rp + (size_t)h0*512;
  float4 xc4 = *(const float4*)(xr0 + c);
  float4 rc4 = *(const float4*)(rr0 + c);
  float  xhv = xr0[cn], rhv = rr0[cn];

  #pragma unroll 2
  for (int k = 0; k < 16; ++k){
    const int h  = h0 + k;
    const int hn = (h+1 < 512) ? h+1 : 511;     // h==511: next==cur -> dh=0
    const float* xr = xp + (size_t)hn*512;
    const float* rr = rp + (size_t)hn*512;
    const float4 nx4 = *(const float4*)(xr + c);
    const float4 nr4 = *(const float4*)(rr + c);
    const float  nxh = xr[cn], nrh = rr[cn];

    const float ax[4] = {xc4.x, xc4.y, xc4.z, xc4.w};
    const float ar[4] = {rc4.x, rc4.y, rc4.z, rc4.w};
    const float bx[4] = {nx4.x, nx4.y, nx4.z, nx4.w};
    const float br[4] = {nr4.x, nr4.y, nr4.z, nr4.w};

    float dv[4], ev[4];
    dv[0]=ax[0]-ax[1]; dv[1]=ax[1]-ax[2]; dv[2]=ax[2]-ax[3];
    ev[0]=ar[0]-ar[1]; ev[1]=ar[1]-ar[2]; ev[2]=ar[2]-ar[3];
    dv[3] = tlast ? 0.f : (ax[3]-xhv);
    ev[3] = tlast ? 0.f : (ar[3]-rhv);

    float p0=0.f,p1=0.f,p2=0.f, q0=0.f,q1=0.f,q2=0.f;
    #pragma unroll
    for (int j = 0; j < 4; ++j){
      p0 = fmaf(dv[j],ev[j],p0); p1 = fmaf(dv[j],dv[j],p1); p2 = fmaf(ev[j],ev[j],p2);
      cv0[j] = fmaf(dv[j],ev[j],cv0[j]);
      cv1[j] = fmaf(dv[j],dv[j],cv1[j]);
      cv2[j] = fmaf(ev[j],ev[j],cv2[j]);
      const float dh = ax[j]-bx[j];
      const float eh = ar[j]-br[j];
      q0 = fmaf(dh,eh,q0); q1 = fmaf(dh,dh,q1); q2 = fmaf(eh,eh,q2);
      ch0[j] = fmaf(dh,eh,ch0[j]);
      ch1[j] = fmaf(dh,dh,ch1[j]);
      ch2[j] = fmaf(eh,eh,ch2[j]);
    }

    // 6 independent DPP chains (VALU pipe)
    p0 = wave_dpp_sum(p0); p1 = wave_dpp_sum(p1); p2 = wave_dpp_sum(p2);
    q0 = wave_dpp_sum(q0); q1 = wave_dpp_sum(q1); q2 = wave_dpp_sum(q2);
    if (l == 63){
      const int rr_ = rg*16 + k;
      rowbuf[rr_][wp][0]=p0; rowbuf[rr_][wp][1]=p1; rowbuf[rr_][wp][2]=p2;
      rowbuf[rr_][wp][3]=q0; rowbuf[rr_][wp][4]=q1; rowbuf[rr_][wp][5]=q2;
    }

    xc4 = nx4; rc4 = nr4; xhv = nxh; rhv = nrh;
  }

  // ---- col merge tree: rg0->A, rg1->B ; rg2+=A, rg3+=B ; store A+B
  if (rg == 0){
    *(float4*)&Abuf[0][c] = make_float4(cv0[0],cv0[1],cv0[2],cv0[3]);
    *(float4*)&Abuf[1][c] = make_float4(cv1[0],cv1[1],cv1[2],cv1[3]);
    *(float4*)&Abuf[2][c] = make_float4(cv2[0],cv2[1],cv2[2],cv2[3]);
    *(float4*)&Abuf[3][c] = make_float4(ch0[0],ch0[1],ch0[2],ch0[3]);
    *(float4*)&Abuf[4][c] = make_float4(ch1[0],ch1[1],ch1[2],ch1[3]);
    *(float4*)&Abuf[5][c] = make_float4(ch2[0],ch2[1],ch2[2],ch2[3]);
  } else if (rg == 1){
    *(float4*)&Bbuf[0][c] = make_float4(cv0[0],cv0[1],cv0[2],cv0[3]);
    *(float4*)&Bbuf[1][c] = make_float4(cv1[0],cv1[1],cv1[2],cv1[3]);
    *(float4*)&Bbuf[2][c] = make_float4(cv2[0],cv2[1],cv2[2],cv2[3]);
    *(float4*)&Bbuf[3][c] = make_float4(ch0[0],ch0[1],ch0[2],ch0[3]);
    *(float4*)&Bbuf[4][c] = make_float4(ch1[0],ch1[1],ch1[2],ch1[3]);
    *(float4*)&Bbuf[5][c] = make_float4(ch2[0],ch2[1],ch2[2],ch2[3]);
  }
  __syncthreads();
  if (rg == 2 || rg == 3){
    float (*buf)[512] = (rg == 2) ? Abuf : Bbuf;
    float4 t;
    t = *(float4*)&buf[0][c]; t.x+=cv0[0]; t.y+=cv0[1]; t.z+=cv0[2]; t.w+=cv0[3]; *(float4*)&buf[0][c]=t;
    t = *(float4*)&buf[1][c]; t.x+=cv1[0]; t.y+=cv1[1]; t.z+=cv1[2]; t.w+=cv1[3]; *(float4*)&buf[1][c]=t;
    t = *(float4*)&buf[2][c]; t.x+=cv2[0]; t.y+=cv2[1]; t.z+=cv2[2]; t.w+=cv2[3]; *(float4*)&buf[2][c]=t;
    t = *(float4*)&buf[3][c]; t.x+=ch0[0]; t.y+=ch0[1]; t.z+=ch0[2]; t.w+=ch0[3]; *(float4*)&buf[3][c]=t;
    t = *(float4*)&buf[4][c]; t.x+=ch1[0]; t.y+=ch1[1]; t.z+=ch1[2]; t.w+=ch1[3]; *(float4*)&buf[4][c]=t;
    t = *(float4*)&buf[5][c]; t.x+=ch2[0]; t.y+=ch2[1]; t.z+=ch2[2]; t.w+=ch2[3]; *(float4*)&buf[5][c]=t;
  }
  __syncthreads();
  {
    const f32x4* A4 = (const f32x4*)Abuf;
    const f32x4* B4 = (const f32x4*)Bbuf;
    f32x4* s4 = (f32x4*)(colPart + (size_t)bid * (6*512));
    for (int idx = tid; idx < 768; idx += 512)
      s4[idx] = A4[idx] + B4[idx];
  }

  // ---- row finalize: wave 0 handles the 64 rows of this band
  if (tid < 64){
    const float a0 = rowbuf[tid][0][0] + rowbuf[tid][1][0];
    const float a1 = rowbuf[tid][0][1] + rowbuf[tid][1][1];
    const float a2 = rowbuf[tid][0][2] + rowbuf[tid][1][2];
    const float b0 = rowbuf[tid][0][3] + rowbuf[tid][1][3];
    const float b1 = rowbuf[tid][0][4] + rowbuf[tid][1][4];
    const float b2 = rowbuf[tid][0][5] + rowbuf[tid][1][5];
    float rv = cos_sim(a0,a1,a2);
    const int h = q*64 + tid;
    float rh = (h < 511) ? cos_sim(b0,b1,b2) : 0.f;
    rv = wave_dpp_sum(rv);
    rh = wave_dpp_sum(rh);
    if (tid == 63){
      rowPart[2*bid+0] = rv;
      rowPart[2*bid+1] = rh;
    }
  }
}

// ---------------- finish: reduce col partials over 8 slots -------------------
__global__ __launch_bounds__(256) void gp_cols(
    const float* __restrict__ colPart, double* __restrict__ dblk)
{
  const int p = blockIdx.x >> 1;
  const int f = blockIdx.x & 1;    // 0 = fv, 1 = fh
  const int tid = threadIdx.x;
  double acc = 0.0;
  for (int c = tid; c < 512; c += 256){
    float d = 0.f, a = 0.f, b = 0.f;
    #pragma unroll
    for (int s = 0; s < 8; ++s){
      const float* sp = colPart + ((size_t)(p*8 + s) * 6 + f*3) * 512;
      d += sp[c]; a += sp[512 + c]; b += sp[1024 + c];
    }
    acc += (double)cos_sim(d, a, b);   // fv col 511: cos(0,0,0)=0, harmless
  }
  #pragma unroll
  for (int m = 1; m < 64; m <<= 1) acc += __shfl_xor(acc, m, 64);
  __shared__ double ls[4];
  const int w = tid >> 6, l = tid & 63;
  if (l == 0) ls[w] = acc;
  __syncthreads();
  if (tid == 0) dblk[blockIdx.x] = ls[0] + ls[1] + ls[2] + ls[3];
}

__global__ __launch_bounds__(256) void gp_fin(
    const double* __restrict__ dblk, const float* __restrict__ rowPart,
    int nblk, float* __restrict__ out)
{
  const int tid = threadIdx.x;
  double rv = 0, rh = 0, cv = 0, ch = 0;
  for (int i = tid; i < nblk; i += 256){
    rv += (double)rowPart[2*i];
    rh += (double)rowPart[2*i+1];
  }
  for (int i = tid; i < 192; i += 256){
    if (i & 1) ch += dblk[i]; else cv += dblk[i];
  }
  #pragma unroll
  for (int m = 1; m < 64; m <<= 1){
    rv += __shfl_xor(rv, m, 64); rh += __shfl_xor(rh, m, 64);
    cv += __shfl_xor(cv, m, 64); ch += __shfl_xor(ch, m, 64);
  }
  __shared__ double ls[4][4];
  const int w = tid >> 6, l = tid & 63;
  if (l == 0){ ls[w][0]=rv; ls[w][1]=rh; ls[w][2]=cv; ls[w][3]=ch; }
  __syncthreads();
  if (tid == 0){
    double RV=0, RH=0, CV=0, CH=0;
    #pragma unroll
    for (int i = 0; i < 4; ++i){ RV+=ls[i][0]; RH+=ls[i][1]; CV+=ls[i][2]; CH+=ls[i][3]; }
    const double t = RV/512.0 + RH/511.0 + CV/511.0 + CH/512.0;
    out[0] = (float)(-t / 32.0);
  }
}

extern "C" void kernel_launch(void* const* d_in, const int* in_sizes, int n_in,
                              void* d_out, int out_size, void* d_ws, size_t ws_size,
                              hipStream_t stream) {
  const float* X = (const float*)d_in[0];
  const float* R = (const float*)d_in[1];
  float* out = (float*)d_out;

  float*  colPart = (float*)d_ws;                         // 768*6*512 f32
  float*  rowPart = colPart + (size_t)768*6*512;          // 768*2 f32
  double* dblk    = (double*)(rowPart + (size_t)768*2);   // 192 f64

  gp_uni <<<dim3(768), dim3(512), 0, stream>>>(X, R, rowPart, colPart);
  gp_cols<<<dim3(192), dim3(256), 0, stream>>>(colPart, dblk);
  gp_fin <<<dim3(1),   dim3(256), 0, stream>>>(dblk, rowPart, 768, out);
}

// Round 16
// 47.373 us; speedup vs baseline: 1.1700x; 1.0673x over previous
//
#include <hip/hip_runtime.h>

// GPLoss: gradient-profile loss, scalar output.
// R15 structure + packed-fp32 arithmetic (v_pk_fma_f32 via <2 x float> fma).
// 768 blocks x 512 thr; block = one 64-row band (8 waves = 4 rowgrps x 2
// colhalves); wave = 16 rows x 256 cols, lane owns 4 cols (float4 loads,
// scalar halo). Row stats: packed pair-accums + horizontal add -> 6 DPP
// chains; col stats: packed accums -> float4 LDS merge tree -> colPart slot
// (768 slots = 9.4 MB, L3-safe). ws: colPart f32[768][6][512] ;
// rowPart f32[768][2] ; dblk f64[192]

typedef float f32x4 __attribute__((ext_vector_type(4)));
typedef float f32x2 __attribute__((ext_vector_type(2)));

__device__ __forceinline__ f32x2 fma2(f32x2 a, f32x2 b, f32x2 c){
  return __builtin_elementwise_fma(a, b, c);
}

#define DPP_ADD(x, ctrl, rmask) \
  x += __int_as_float(__builtin_amdgcn_update_dpp(0, __float_as_int(x), ctrl, rmask, 0xf, false))

__device__ __forceinline__ float wave_dpp_sum(float x){
  DPP_ADD(x, 0x111, 0xf);   // row_shr:1
  DPP_ADD(x, 0x112, 0xf);   // row_shr:2
  DPP_ADD(x, 0x114, 0xf);   // row_shr:4
  DPP_ADD(x, 0x118, 0xf);   // row_shr:8
  DPP_ADD(x, 0x142, 0xa);   // row_bcast:15 -> rows 1,3
  DPP_ADD(x, 0x143, 0xc);   // row_bcast:31 -> rows 2,3
  return x;                 // lane 63 holds the 64-lane sum
}

__device__ __forceinline__ float cos_sim(float d, float sx, float sr){
  float nx = fmaxf(sqrtf(sx), 1e-12f);
  float nr = fmaxf(sqrtf(sr), 1e-12f);
  return d / (nx * nr);
}

__global__ __launch_bounds__(512) void gp_uni(
    const float* __restrict__ X, const float* __restrict__ R,
    float* __restrict__ rowPart, float* __restrict__ colPart)
{
  const int bid = blockIdx.x;
  const int p = bid >> 3, q = bid & 7;         // plane, 64-row band
  const int tid = threadIdx.x, w = tid >> 6, l = tid & 63;
  const int rg = w >> 1;                        // row-group 0..3
  const int wp = w & 1;                         // col half: wp*256
  const size_t plane = (size_t)p * (512u * 512u);
  const float* xp = X + plane;
  const float* rp = R + plane;
  const int c  = wp*256 + 4*l;                  // cols c..c+3
  const int cn = (c+4 < 512) ? c+4 : 511;       // f_v halo col (clamped)
  const bool tlast = (c == 508);                // col 511: no f_v
  const int h0 = q*64 + rg*16;                  // first row of this wave

  __shared__ float Abuf[6][512];                // 12 KB (rowgrps 0,2)
  __shared__ float Bbuf[6][512];                // 12 KB (rowgrps 1,3)
  __shared__ float rowbuf[64][2][6];            // 3 KB row stats

  // packed column accumulators: [0] = cols c,c+1 ; [1] = cols c+2,c+3
  f32x2 cv0a={0.f,0.f}, cv0b={0.f,0.f}, cv1a={0.f,0.f}, cv1b={0.f,0.f};
  f32x2 cv2a={0.f,0.f}, cv2b={0.f,0.f}, ch0a={0.f,0.f}, ch0b={0.f,0.f};
  f32x2 ch1a={0.f,0.f}, ch1b={0.f,0.f}, ch2a={0.f,0.f}, ch2b={0.f,0.f};

  const float* xr0 = xp + (size_t)h0*512;
  const float* rr0 = rp + (size_t)h0*512;
  float4 xc4 = *(const float4*)(xr0 + c);
  float4 rc4 = *(const float4*)(rr0 + c);
  float  xhv = xr0[cn], rhv = rr0[cn];

  #pragma unroll 2
  for (int k = 0; k < 16; ++k){
    const int h  = h0 + k;
    const int hn = (h+1 < 512) ? h+1 : 511;     // h==511: next==cur -> dh=0
    const float* xr = xp + (size_t)hn*512;
    const float* rr = rp + (size_t)hn*512;
    const float4 nx4 = *(const float4*)(xr + c);
    const float4 nr4 = *(const float4*)(rr + c);
    const float  nxh = xr[cn], nrh = rr[cn];

    // packed current/next/shifted row vectors
    const f32x2 ax01 = {xc4.x, xc4.y}, ax23 = {xc4.z, xc4.w};
    const f32x2 ar01 = {rc4.x, rc4.y}, ar23 = {rc4.z, rc4.w};
    const f32x2 bx01 = {nx4.x, nx4.y}, bx23 = {nx4.z, nx4.w};
    const f32x2 br01 = {nr4.x, nr4.y}, br23 = {nr4.z, nr4.w};
    const f32x2 sx01 = {xc4.y, xc4.z}, sx23 = {xc4.w, tlast ? xc4.w : xhv};
    const f32x2 sr01 = {rc4.y, rc4.z}, sr23 = {rc4.w, tlast ? rc4.w : rhv};

    const f32x2 dv01 = ax01 - sx01, dv23 = ax23 - sx23;   // dv3=0 when tlast
    const f32x2 ev01 = ar01 - sr01, ev23 = ar23 - sr23;
    const f32x2 dh01 = ax01 - bx01, dh23 = ax23 - bx23;
    const f32x2 eh01 = ar01 - br01, eh23 = ar23 - br23;

    // row stats: packed pair-accum then horizontal add
    f32x2 p0v = dv01*ev01; p0v = fma2(dv23, ev23, p0v);
    f32x2 p1v = dv01*dv01; p1v = fma2(dv23, dv23, p1v);
    f32x2 p2v = ev01*ev01; p2v = fma2(ev23, ev23, p2v);
    f32x2 q0v = dh01*eh01; q0v = fma2(dh23, eh23, q0v);
    f32x2 q1v = dh01*dh01; q1v = fma2(dh23, dh23, q1v);
    f32x2 q2v = eh01*eh01; q2v = fma2(eh23, eh23, q2v);

    // col accumulators (packed)
    cv0a = fma2(dv01, ev01, cv0a); cv0b = fma2(dv23, ev23, cv0b);
    cv1a = fma2(dv01, dv01, cv1a); cv1b = fma2(dv23, dv23, cv1b);
    cv2a = fma2(ev01, ev01, cv2a); cv2b = fma2(ev23, ev23, cv2b);
    ch0a = fma2(dh01, eh01, ch0a); ch0b = fma2(dh23, eh23, ch0b);
    ch1a = fma2(dh01, dh01, ch1a); ch1b = fma2(dh23, dh23, ch1b);
    ch2a = fma2(eh01, eh01, ch2a); ch2b = fma2(eh23, eh23, ch2b);

    float p0 = p0v.x + p0v.y, p1 = p1v.x + p1v.y, p2 = p2v.x + p2v.y;
    float q0 = q0v.x + q0v.y, q1 = q1v.x + q1v.y, q2 = q2v.x + q2v.y;

    // 6 independent DPP chains (VALU pipe)
    p0 = wave_dpp_sum(p0); p1 = wave_dpp_sum(p1); p2 = wave_dpp_sum(p2);
    q0 = wave_dpp_sum(q0); q1 = wave_dpp_sum(q1); q2 = wave_dpp_sum(q2);
    if (l == 63){
      const int rr_ = rg*16 + k;
      rowbuf[rr_][wp][0]=p0; rowbuf[rr_][wp][1]=p1; rowbuf[rr_][wp][2]=p2;
      rowbuf[rr_][wp][3]=q0; rowbuf[rr_][wp][4]=q1; rowbuf[rr_][wp][5]=q2;
    }

    xc4 = nx4; rc4 = nr4; xhv = nxh; rhv = nrh;
  }

  // ---- col merge tree: rg0->A, rg1->B ; rg2+=A, rg3+=B ; store A+B
  if (rg == 0){
    *(float4*)&Abuf[0][c] = make_float4(cv0a.x,cv0a.y,cv0b.x,cv0b.y);
    *(float4*)&Abuf[1][c] = make_float4(cv1a.x,cv1a.y,cv1b.x,cv1b.y);
    *(float4*)&Abuf[2][c] = make_float4(cv2a.x,cv2a.y,cv2b.x,cv2b.y);
    *(float4*)&Abuf[3][c] = make_float4(ch0a.x,ch0a.y,ch0b.x,ch0b.y);
    *(float4*)&Abuf[4][c] = make_float4(ch1a.x,ch1a.y,ch1b.x,ch1b.y);
    *(float4*)&Abuf[5][c] = make_float4(ch2a.x,ch2a.y,ch2b.x,ch2b.y);
  } else if (rg == 1){
    *(float4*)&Bbuf[0][c] = make_float4(cv0a.x,cv0a.y,cv0b.x,cv0b.y);
    *(float4*)&Bbuf[1][c] = make_float4(cv1a.x,cv1a.y,cv1b.x,cv1b.y);
    *(float4*)&Bbuf[2][c] = make_float4(cv2a.x,cv2a.y,cv2b.x,cv2b.y);
    *(float4*)&Bbuf[3][c] = make_float4(ch0a.x,ch0a.y,ch0b.x,ch0b.y);
    *(float4*)&Bbuf[4][c] = make_float4(ch1a.x,ch1a.y,ch1b.x,ch1b.y);
    *(float4*)&Bbuf[5][c] = make_float4(ch2a.x,ch2a.y,ch2b.x,ch2b.y);
  }
  __syncthreads();
  if (rg == 2 || rg == 3){
    float (*buf)[512] = (rg == 2) ? Abuf : Bbuf;
    float4 t;
    t = *(float4*)&buf[0][c]; t.x+=cv0a.x; t.y+=cv0a.y; t.z+=cv0b.x; t.w+=cv0b.y; *(float4*)&buf[0][c]=t;
    t = *(float4*)&buf[1][c]; t.x+=cv1a.x; t.y+=cv1a.y; t.z+=cv1b.x; t.w+=cv1b.y; *(float4*)&buf[1][c]=t;
    t = *(float4*)&buf[2][c]; t.x+=cv2a.x; t.y+=cv2a.y; t.z+=cv2b.x; t.w+=cv2b.y; *(float4*)&buf[2][c]=t;
    t = *(float4*)&buf[3][c]; t.x+=ch0a.x; t.y+=ch0a.y; t.z+=ch0b.x; t.w+=ch0b.y; *(float4*)&buf[3][c]=t;
    t = *(float4*)&buf[4][c]; t.x+=ch1a.x; t.y+=ch1a.y; t.z+=ch1b.x; t.w+=ch1b.y; *(float4*)&buf[4][c]=t;
    t = *(float4*)&buf[5][c]; t.x+=ch2a.x; t.y+=ch2a.y; t.z+=ch2b.x; t.w+=ch2b.y; *(float4*)&buf[5][c]=t;
  }
  __syncthreads();
  {
    const f32x4* A4 = (const f32x4*)Abuf;
    const f32x4* B4 = (const f32x4*)Bbuf;
    f32x4* s4 = (f32x4*)(colPart + (size_t)bid * (6*512));
    for (int idx = tid; idx < 768; idx += 512)
      s4[idx] = A4[idx] + B4[idx];
  }

  // ---- row finalize: wave 0 handles the 64 rows of this band
  if (tid < 64){
    const float a0 = rowbuf[tid][0][0] + rowbuf[tid][1][0];
    const float a1 = rowbuf[tid][0][1] + rowbuf[tid][1][1];
    const float a2 = rowbuf[tid][0][2] + rowbuf[tid][1][2];
    const float b0 = rowbuf[tid][0][3] + rowbuf[tid][1][3];
    const float b1 = rowbuf[tid][0][4] + rowbuf[tid][1][4];
    const float b2 = rowbuf[tid][0][5] + rowbuf[tid][1][5];
    float rv = cos_sim(a0,a1,a2);
    const int h = q*64 + tid;
    float rh = (h < 511) ? cos_sim(b0,b1,b2) : 0.f;
    rv = wave_dpp_sum(rv);
    rh = wave_dpp_sum(rh);
    if (tid == 63){
      rowPart[2*bid+0] = rv;
      rowPart[2*bid+1] = rh;
    }
  }
}

// ---------------- finish: reduce col partials over 8 slots -------------------
__global__ __launch_bounds__(256) void gp_cols(
    const float* __restrict__ colPart, double* __restrict__ dblk)
{
  const int p = blockIdx.x >> 1;
  const int f = blockIdx.x & 1;    // 0 = fv, 1 = fh
  const int tid = threadIdx.x;
  double acc = 0.0;
  for (int c = tid; c < 512; c += 256){
    float d = 0.f, a = 0.f, b = 0.f;
    #pragma unroll
    for (int s = 0; s < 8; ++s){
      const float* sp = colPart + ((size_t)(p*8 + s) * 6 + f*3) * 512;
      d += sp[c]; a += sp[512 + c]; b += sp[1024 + c];
    }
    acc += (double)cos_sim(d, a, b);   // fv col 511: cos(0,0,0)=0, harmless
  }
  #pragma unroll
  for (int m = 1; m < 64; m <<= 1) acc += __shfl_xor(acc, m, 64);
  __shared__ double ls[4];
  const int w = tid >> 6, l = tid & 63;
  if (l == 0) ls[w] = acc;
  __syncthreads();
  if (tid == 0) dblk[blockIdx.x] = ls[0] + ls[1] + ls[2] + ls[3];
}

__global__ __launch_bounds__(256) void gp_fin(
    const double* __restrict__ dblk, const float* __restrict__ rowPart,
    int nblk, float* __restrict__ out)
{
  const int tid = threadIdx.x;
  double rv = 0, rh = 0, cv = 0, ch = 0;
  for (int i = tid; i < nblk; i += 256){
    rv += (double)rowPart[2*i];
    rh += (double)rowPart[2*i+1];
  }
  for (int i = tid; i < 192; i += 256){
    if (i & 1) ch += dblk[i]; else cv += dblk[i];
  }
  #pragma unroll
  for (int m = 1; m < 64; m <<= 1){
    rv += __shfl_xor(rv, m, 64); rh += __shfl_xor(rh, m, 64);
    cv += __shfl_xor(cv, m, 64); ch += __shfl_xor(ch, m, 64);
  }
  __shared__ double ls[4][4];
  const int w = tid >> 6, l = tid & 63;
  if (l == 0){ ls[w][0]=rv; ls[w][1]=rh; ls[w][2]=cv; ls[w][3]=ch; }
  __syncthreads();
  if (tid == 0){
    double RV=0, RH=0, CV=0, CH=0;
    #pragma unroll
    for (int i = 0; i < 4; ++i){ RV+=ls[i][0]; RH+=ls[i][1]; CV+=ls[i][2]; CH+=ls[i][3]; }
    const double t = RV/512.0 + RH/511.0 + CV/511.0 + CH/512.0;
    out[0] = (float)(-t / 32.0);
  }
}

extern "C" void kernel_launch(void* const* d_in, const int* in_sizes, int n_in,
                              void* d_out, int out_size, void* d_ws, size_t ws_size,
                              hipStream_t stream) {
  const float* X = (const float*)d_in[0];
  const float* R = (const float*)d_in[1];
  float* out = (float*)d_out;

  float*  colPart = (float*)d_ws;                         // 768*6*512 f32
  float*  rowPart = colPart + (size_t)768*6*512;          // 768*2 f32
  double* dblk    = (double*)(rowPart + (size_t)768*2);   // 192 f64

  gp_uni <<<dim3(768), dim3(512), 0, stream>>>(X, R, rowPart, colPart);
  gp_cols<<<dim3(192), dim3(256), 0, stream>>>(colPart, dblk);
  gp_fin <<<dim3(1),   dim3(256), 0, stream>>>(dblk, rowPart, 768, out);
}